// Round 5
// baseline (1956.290 us; speedup 1.0000x reference)
//
#include <hip/hip_runtime.h>
#include <math.h>

#define NN 4096
#define STRIPS 32
#define SW 128                        // strip width (columns per workgroup)
#define RING_ROWS 128                 // power of 2: ring slot = row & 127
#define BATCH 16
#define PAD 64                        // colbuf per-strip padding rows
#define COLPITCH (NN + 2 * PAD)
#define INFV 1e30f
#define SENTU 0xFFFFFFFFu             // memset(0xFF) sentinel, never a DP result

// lane l <- lane l-1 (whole-wave shift right by 1), VALU-latency cross-lane move
__device__ __forceinline__ float dpp_wave_shr1(float x) {
    return __int_as_float(__builtin_amdgcn_update_dpp(
        0, __float_as_int(x), 0x138 /*WAVE_SHR1*/, 0xf, 0xf, false));
}

// lanes 0..15 load boundary rows [row, row+16) of the left strip's column.
// MODE 2: inline-asm load with sc0 sc1 (forced device/LLC scope).
template <int MODE>
__device__ __forceinline__ float bload(const unsigned* colL, int row, int lane) {
    float v = INFV;
    if (lane < 16 && row < NN) {
        unsigned u;
        if (MODE == 2) {
            const unsigned* p = colL + row;
            asm volatile("global_load_dword %0, %1, off sc0 sc1\n\t"
                         "s_waitcnt vmcnt(0)"
                         : "=v"(u) : "v"(p) : "memory");
        } else {
            u = __hip_atomic_load(colL + row, __ATOMIC_RELAXED,
                                  __HIP_MEMORY_SCOPE_AGENT);
        }
        v = __uint_as_float(u);
    }
    return v;
}

template <int MODE>
__device__ __forceinline__ void pstore(unsigned* addr, float val) {
    if (MODE == 2) {
        asm volatile("global_store_dword %0, %1, off sc0 sc1"
                     :: "v"(addr), "v"(__float_as_uint(val)) : "memory");
    } else {
        __hip_atomic_store(addr, __float_as_uint(val), __ATOMIC_RELAXED,
                           __HIP_MEMORY_SCOPE_AGENT);
    }
}

// rows [rb, rb+16) still hold the memset sentinel? (rows >= NN masked off)
__device__ __forceinline__ bool has_sent(float b, int rb, int lane) {
    return __any((lane < 16) && ((rb + lane) < NN) &&
                 (__float_as_uint(b) == SENTU));
}

// async-stage rows [rb, rb+16) (128 cols) into the LDS ring at slot (row&127).
__device__ __forceinline__ void stage16(const float* Dg, float* ring, int rb,
                                        int lane) {
    #pragma unroll
    for (int k = 0; k < 8; ++k) {
        const int r0 = rb + 2 * k;
        if (r0 < NN) {
            const int slot = r0 & (RING_ROWS - 1);
            const float* gsrc =
                Dg + (size_t)(r0 + (lane >> 5)) * NN + ((lane & 31) << 2);
            __builtin_amdgcn_global_load_lds(
                (const __attribute__((address_space(1))) unsigned*)gsrc,
                (__attribute__((address_space(3))) unsigned*)((char*)ring +
                                                             slot * (SW * 4)),
                16, 0, 0);
        }
    }
}

// ---------------------------------------------------------------------------
// MODE 0: real (intrinsic agent atomics). MODE 1: no inter-strip comm
// (free-running per-strip cost probe). MODE 2: asm sc0 sc1 comm.
// ---------------------------------------------------------------------------
template <int MODE>
__global__ __launch_bounds__(64) void dtw_dp(const float* __restrict__ D,
                                             float* __restrict__ cost_out,
                                             unsigned* __restrict__ colbuf,
                                             unsigned* __restrict__ dummy) {
    __shared__ float ring[RING_ROWS * SW];   // 64 KB

    const int g = blockIdx.x;
    const int lane = threadIdx.x;
    const float* Dg = D + g * SW;
    const unsigned* colL = colbuf + (size_t)(g - 1) * COLPITCH + PAD;
    unsigned* colM = colbuf + (size_t)g * COLPITCH + PAD;
    const bool lane0 = (lane == 0);
    const bool comm = (MODE != 1) && (g > 0);

    // clear pre-start ring slots [64,128) (read before ever staged; must be
    // finite, non-NaN). 64 rows x 512 B = 32 KB.
    {
        const float4 z = make_float4(0.f, 0.f, 0.f, 0.f);
        float4* r4 = reinterpret_cast<float4*>(&ring[64 * SW]);
        #pragma unroll
        for (int i = 0; i < 32; ++i) r4[i * 64 + lane] = z;
    }

    // prologue: stage rows [0,32); fill boundary queue (bv valid, bvn pending)
    stage16(Dg, ring, 0, lane);
    stage16(Dg, ring, 16, lane);
    float bv = INFV, bvn = INFV;
    if (comm) {
        bv = bload<MODE>(colL, lane, lane);
        while (has_sent(bv, 0, lane)) bv = bload<MODE>(colL, lane, lane);
        bvn = bload<MODE>(colL, 16 + lane, lane);
    }

    // publish pointer walk: lane 63 walks its column (starting at row -63,
    // inside the pad); all other lanes walk a shared dummy sink. One
    // unconditional store per step -> zero exec-mask manipulation.
    unsigned* staddr = (lane == 63) ? (colM - 63) : (dummy + lane);

    float cur0 = INFV, cur1 = INFV;   // my c[r-1][2l], c[r-1][2l+1]
    float l1s = INFV, l2s = INFV;     // lane l-1's c1 from t-1, t-2
    float bprevc = INFV;              // boundary row tb-1 carry
    float save = 0.f;                 // c1 at the final cell (strip 31)

    for (int tb = 0; tb < NN + 64; tb += BATCH) {   // 260 batches
        float bvp = INFV;
        if (comm) {
            // validate rows [tb+16,tb+32) one batch before use; steady: no spin
            while (has_sent(bvn, tb + 16, lane))
                bvn = bload<MODE>(colL, tb + 16 + lane, lane);
            bvp = bload<MODE>(colL, tb + 32 + lane, lane);  // 2 batches ahead
        }

        // hoist boundary values to scalars (off the serial chain)
        float bc[BATCH];
        #pragma unroll
        for (int s = 0; s < BATCH; ++s) {
            bc[s] = __int_as_float(
                __builtin_amdgcn_readlane(__float_as_int(bv), s));
            if (g == 0) bc[s] = INFV;
        }
        if (g == 0 && tb == 0) bc[0] = 0.f;   // the (0,0) corner: m0 = 0

        // stage rows [tb+32,tb+48); guard rows [tb,tb+16) staged 2 batches ago.
        // Newer-op count after that stage: >=48 in steady state for every
        // strip; early/tail batches fall back to a full drain.
        stage16(Dg, ring, tb + 32, lane);
        __builtin_amdgcn_sched_barrier(0);
        if (tb >= 32 && tb + 47 < NN) {
            asm volatile("s_waitcnt vmcnt(48)" ::: "memory");
        } else {
            asm volatile("s_waitcnt vmcnt(0)" ::: "memory");
        }
        __builtin_amdgcn_sched_barrier(0);

        // grouped LDS -> register reads for the whole batch
        float2 rv[BATCH];
        #pragma unroll
        for (int s = 0; s < BATCH; ++s) {
            const int r = tb + s - lane;
            rv[s] = *reinterpret_cast<const float2*>(
                &ring[(r & (RING_ROWS - 1)) * SW + 2 * lane]);
        }
        __builtin_amdgcn_sched_barrier(0);

        #pragma unroll
        for (int s = 0; s < BATCH; ++s) {
            const float e0 = __expf(-rv[s].x);
            const float e1 = __expf(-rv[s].y);
            // lane-0 boundary feeds; col 0 of the matrix (g==0) has none
            const float bcur = bc[s];
            const float bpv =
                (g == 0) ? INFV : ((s == 0) ? bprevc : bc[s - 1]);
            // chain: cndmask -> min3 -> add -> fmin -> add -> dpp
            const float L1 = lane0 ? bcur : l1s;   // c[r][col-1]
            const float L2 = lane0 ? bpv : l2s;    // c[r-1][col-1]
            const float m0 = fminf(fminf(L1, cur0), L2);
            const float c0 = e0 + m0;
            const float c1 = e1 + fminf(c0, fminf(cur0, cur1));
            pstore<MODE>(staddr, c1);              // lane63 -> column, rest -> sink
            staddr += 1;
            const float sh = dpp_wave_shr1(c1);
            l2s = l1s; l1s = sh;
            cur0 = c0; cur1 = c1;
            if (s == 14) save = c1;                // final cell lands here
        }
        bprevc = bc[BATCH - 1];
        bv = bvn; bvn = bvp;
    }

    if (g == STRIPS - 1 && lane == 63) cost_out[0] = save;
}

// ---------------------------------------------------------------------------
// acc_grad[i,j] = d[i+1,j+1] + d[i+1,j] + d[i,j+1] - d[i,j],  d = exp(-exp(-D))
// ---------------------------------------------------------------------------
__device__ __forceinline__ float dfun(float x) { return __expf(-__expf(-x)); }

__global__ __launch_bounds__(256) void dtw_grad_kernel(const float* __restrict__ D,
                                                       float* __restrict__ G) {
    const int idx = blockIdx.x * 256 + threadIdx.x;
    const int i = idx >> 10;
    const int j = (idx & 1023) << 2;
    if (i >= NN) return;

    const float* row0 = D + (size_t)i * NN + j;
    const bool hasR = (i + 1) < NN;
    const bool hasC = (j + 4) < NN;

    const float4 r0 = *reinterpret_cast<const float4*>(row0);
    float4 r1 = make_float4(0.f, 0.f, 0.f, 0.f);
    if (hasR) r1 = *reinterpret_cast<const float4*>(row0 + NN);
    const float s0 = hasC ? row0[4] : 0.f;
    const float s1 = (hasR && hasC) ? row0[NN + 4] : 0.f;

    const float a0 = dfun(r0.x), a1 = dfun(r0.y), a2 = dfun(r0.z), a3 = dfun(r0.w);
    const float a4 = hasC ? dfun(s0) : 0.f;
    const float b0 = hasR ? dfun(r1.x) : 0.f;
    const float b1 = hasR ? dfun(r1.y) : 0.f;
    const float b2 = hasR ? dfun(r1.z) : 0.f;
    const float b3 = hasR ? dfun(r1.w) : 0.f;
    const float b4 = (hasR && hasC) ? dfun(s1) : 0.f;

    float* go = G + (size_t)i * NN + j;
    go[0] = b1 + b0 + a1 - a0;
    go[1] = b2 + b1 + a2 - a1;
    go[2] = b3 + b2 + a3 - a2;
    go[3] = b4 + b3 + a4 - a3;
}

// ---------------------------------------------------------------------------
extern "C" void kernel_launch(void* const* d_in, const int* in_sizes, int n_in,
                              void* d_out, int out_size, void* d_ws, size_t ws_size,
                              hipStream_t stream) {
    (void)in_sizes; (void)n_in; (void)out_size;
    const float* D = (const float*)d_in[0];
    float* out = (float*)d_out;

    const size_t colbytes = (size_t)STRIPS * COLPITCH * sizeof(unsigned);
    const size_t dummybytes = 32 * 1024;
    const size_t need = 2 * colbytes + dummybytes + 256;

    unsigned *colA, *colC = nullptr, *dummy;
    float *costB = nullptr, *costC = nullptr;
    const bool useWs = (ws_size >= need);
    if (useWs) {
        char* w = (char*)d_ws;
        colA = (unsigned*)w;
        colC = (unsigned*)(w + colbytes);
        dummy = (unsigned*)(w + 2 * colbytes);
        costB = (float*)(w + 2 * colbytes + dummybytes);
        costC = costB + 2;
    } else {
        // fallback: live inside the grad region (rewritten by grad kernel)
        char* w = (char*)(out + 1);
        colA = (unsigned*)w;
        dummy = (unsigned*)(w + colbytes);
    }

    // --- A: real dispatch (validated output) ---
    hipMemsetAsync(colA, 0xFF, colbytes, stream);
    dtw_dp<0><<<STRIPS, 64, 0, stream>>>(D, out, colA, dummy);

    if (useWs) {
        // --- B: no-comm probe (free-running per-strip cost) ---
        dtw_dp<1><<<STRIPS, 64, 0, stream>>>(D, costB, colC, dummy);
        // --- C: asm sc0/sc1 comm probe ---
        hipMemsetAsync(colC, 0xFF, colbytes, stream);
        dtw_dp<2><<<STRIPS, 64, 0, stream>>>(D, costC, colC, dummy);
    }

    dtw_grad_kernel<<<dim3((NN * (NN / 4)) / 256), dim3(256), 0, stream>>>(D, out + 1);
}

// Round 6
// 1541.646 us; speedup vs baseline: 1.2690x; 1.2690x over previous
//
#include <hip/hip_runtime.h>
#include <math.h>

#define NN 4096
#define STRIPS 32
#define SW 128                        // strip width (columns per workgroup)
#define RING_ROWS 128                 // power of 2: ring slot = row & 127
#define BATCH 32
#define PAD 64                        // colbuf per-strip padding rows
#define COLPITCH (NN + 2 * PAD)
#define SINKPITCH 4352                // dwords per strip sink (walked 4160 + 64 lanes)
#define INFV 1e30f
#define SENTU 0xFFFFFFFFu             // memset(0xFF) sentinel, never a DP result

// lane l <- lane l-1 (whole-wave shift right by 1), VALU-latency cross-lane move
__device__ __forceinline__ float dpp_wave_shr1(float x) {
    return __int_as_float(__builtin_amdgcn_update_dpp(
        0, __float_as_int(x), 0x138 /*WAVE_SHR1*/, 0xf, 0xf, false));
}

// lanes 0..31 load boundary rows [row, row+32) of the left strip's column
__device__ __forceinline__ float bload(const unsigned* colL, int row, int lane) {
    float v = INFV;
    if (lane < BATCH && row < NN) {
        unsigned u = __hip_atomic_load(colL + row, __ATOMIC_RELAXED,
                                       __HIP_MEMORY_SCOPE_AGENT);
        v = __uint_as_float(u);
    }
    return v;
}

// rows [rb, rb+32) still hold the memset sentinel? (rows >= NN masked off)
__device__ __forceinline__ bool has_sent(float b, int rb, int lane) {
    return __any((lane < BATCH) && ((rb + lane) < NN) &&
                 (__float_as_uint(b) == SENTU));
}

// async-stage rows [rb, rb+32) (128 cols) into the LDS ring at slot (row&127).
// 16 x global_load_lds (16B/lane); each covers 2 rows (lanes 0-31 / 32-63).
__device__ __forceinline__ void stageB(const float* Sg, float* ring, int rb,
                                       int lane) {
    #pragma unroll
    for (int k = 0; k < BATCH / 2; ++k) {
        const int r0 = rb + 2 * k;
        if (r0 < NN) {
            const int slot = r0 & (RING_ROWS - 1);
            const float* gsrc =
                Sg + (size_t)(r0 + (lane >> 5)) * NN + ((lane & 31) << 2);
            __builtin_amdgcn_global_load_lds(
                (const __attribute__((address_space(1))) unsigned*)gsrc,
                (__attribute__((address_space(3))) unsigned*)((char*)ring +
                                                             slot * (SW * 4)),
                16, 0, 0);
        }
    }
}

// ---------------------------------------------------------------------------
// DP: 32 workgroups x 1 wave. Strip g owns cols [128g, 128g+128); lane l owns
// cols 2l, 2l+1; at step t lane l computes row r = t - l. Left/diag neighbor
// values via DPP wave_shr1. Strip boundary flows through agent-scope colbuf
// with a 3-deep register queue (consume / validated-ahead / prefetched), so
// the steady state is spin-free. DOEXP=1: input is raw D (compute exp(-D) on
// the fly); DOEXP=0: input is precomputed E (pure min/add chain).
// vmcnt guards: counted (49 comm / 48 no-comm = stores(32)+bvp(1)+stage(16))
// only when the batch op-count is deterministic (no spin, full stages).
// ---------------------------------------------------------------------------
template <int DOEXP>
__global__ __launch_bounds__(64) void dtw_dp(const float* __restrict__ S,
                                             float* __restrict__ cost_out,
                                             unsigned* __restrict__ colbuf,
                                             unsigned* __restrict__ sinkbase) {
    __shared__ float ring[RING_ROWS * SW];   // 64 KB

    const int g = blockIdx.x;
    const int lane = threadIdx.x;
    const float* Sg = S + g * SW;
    const unsigned* colL = colbuf + (size_t)(g - 1) * COLPITCH + PAD;
    unsigned* colM = colbuf + (size_t)g * COLPITCH + PAD;
    const bool comm = (g > 0);
    const bool lane0 = (lane == 0);

    // clear pre-start ring slots [64,128): rows r<0 read here; 0 keeps the
    // INF chain intact (INF + 0 = INF).
    {
        const float4 z = make_float4(0.f, 0.f, 0.f, 0.f);
        float4* r4 = reinterpret_cast<float4*>(&ring[64 * SW]);
        #pragma unroll
        for (int i = 0; i < 32; ++i) r4[i * 64 + lane] = z;
    }

    // prologue: stage rows [0,32); fill boundary queue
    stageB(Sg, ring, 0, lane);
    float bv = INFV, bvn = INFV;
    if (comm) {
        bv = bload(colL, lane, lane);
        while (has_sent(bv, 0, lane)) bv = bload(colL, lane, lane);
        bvn = bload(colL, BATCH + lane, lane);
    }

    // publish walk: lane 63 walks its column (from row -63, inside the pad);
    // other lanes walk a PER-STRIP private sink (no cross-CU hot lines).
    unsigned* staddr = (lane == 63)
                           ? (colM - 63)
                           : (sinkbase + (size_t)g * SINKPITCH + lane);

    float cur0 = INFV, cur1 = INFV;   // my c[r-1][2l], c[r-1][2l+1]
    float l1s = INFV, l2s = INFV;     // lane l-1's c1 from t-1, t-2
    float bprevc = INFV;              // boundary carry (row tb-1)
    float save = 0.f;                 // c1 at the final cell (strip 31)

    for (int tb = 0; tb < NN + 64; tb += BATCH) {   // 130 batches
        bool spun = false;
        float bvp = INFV;
        if (comm) {
            // validate rows [tb+32,tb+64) one batch before use; steady: no spin
            while (has_sent(bvn, tb + BATCH, lane)) {
                spun = true;
                bvn = bload(colL, tb + BATCH + lane, lane);
            }
            bvp = bload(colL, tb + 2 * BATCH + lane, lane);  // 2 batches ahead
        }
        __builtin_amdgcn_sched_barrier(0);

        // stage rows [tb+32, tb+64) (used NEXT batch; 1-batch-ahead)
        stageB(Sg, ring, tb + BATCH, lane);
        __builtin_amdgcn_sched_barrier(0);

        // guard rows [tb, tb+32): staged last batch. Counted guard only when
        // op counts are deterministic (no spin this batch, full stages, past
        // the prologue): newest ops = stores(32)+bvp(0/1)+stage(16).
        const bool steady = (tb >= 64) && (tb + 96 <= NN) && !spun;
        if (steady) {
            if (comm) asm volatile("s_waitcnt vmcnt(49)" ::: "memory");
            else      asm volatile("s_waitcnt vmcnt(48)" ::: "memory");
        } else {
            asm volatile("s_waitcnt vmcnt(0)" ::: "memory");
        }
        __builtin_amdgcn_sched_barrier(0);

        // grouped LDS -> register reads for the whole batch
        float2 rv[BATCH];
        #pragma unroll
        for (int s = 0; s < BATCH; ++s) {
            const int r = tb + s - lane;
            rv[s] = *reinterpret_cast<const float2*>(
                &ring[(r & (RING_ROWS - 1)) * SW + 2 * lane]);
        }
        __builtin_amdgcn_sched_barrier(0);

        // hoist boundary values to scalars (off the serial chain)
        float bc[BATCH];
        #pragma unroll
        for (int s = 0; s < BATCH; ++s) {
            bc[s] = __int_as_float(
                __builtin_amdgcn_readlane(__float_as_int(bv), s));
            if (g == 0) bc[s] = INFV;
        }
        if (g == 0 && tb == 0) bc[0] = 0.f;   // the (0,0) corner: m0 = 0

        #pragma unroll
        for (int s = 0; s < BATCH; ++s) {
            float e0, e1;
            if (DOEXP) { e0 = __expf(-rv[s].x); e1 = __expf(-rv[s].y); }
            else       { e0 = rv[s].x;          e1 = rv[s].y; }
            const float bcur = bc[s];
            const float bpv =
                (g == 0) ? INFV : ((s == 0) ? bprevc : bc[s - 1]);
            // chain: cndmask -> min3 -> add -> fmin -> add -> dpp
            const float L1 = lane0 ? bcur : l1s;   // c[r][col-1]
            const float L2 = lane0 ? bpv : l2s;    // c[r-1][col-1]
            const float m0 = fminf(fminf(L1, cur0), L2);
            const float c0 = e0 + m0;
            const float c1 = e1 + fminf(c0, fminf(cur0, cur1));
            __hip_atomic_store(staddr, __float_as_uint(c1), __ATOMIC_RELAXED,
                               __HIP_MEMORY_SCOPE_AGENT);
            staddr += 1;
            const float sh = dpp_wave_shr1(c1);
            l2s = l1s; l1s = sh;
            cur0 = c0; cur1 = c1;
            if (s == 30) save = c1;   // final cell: t=NN+62 -> tb=4128, s=30
        }
        bprevc = bc[BATCH - 1];
        bv = bvn; bvn = bvp;
    }

    if (g == STRIPS - 1 && lane == 63) cost_out[0] = save;
}

// ---------------------------------------------------------------------------
// E = exp(-D), elementwise, full-occupancy (memory-bound, ~21 us at HBM BW)
// ---------------------------------------------------------------------------
__global__ __launch_bounds__(256) void exp_pre(const float* __restrict__ D,
                                               float* __restrict__ E) {
    const int n4 = NN * NN / 4;
    for (int i = blockIdx.x * 256 + threadIdx.x; i < n4; i += 2048 * 256) {
        float4 v = reinterpret_cast<const float4*>(D)[i];
        v.x = __expf(-v.x); v.y = __expf(-v.y);
        v.z = __expf(-v.z); v.w = __expf(-v.w);
        reinterpret_cast<float4*>(E)[i] = v;
    }
}

// ---------------------------------------------------------------------------
// acc_grad[i,j] = d[i+1,j+1] + d[i+1,j] + d[i,j+1] - d[i,j],  d = exp(-exp(-D))
// ---------------------------------------------------------------------------
__device__ __forceinline__ float dfun(float x) { return __expf(-__expf(-x)); }

__global__ __launch_bounds__(256) void dtw_grad_kernel(const float* __restrict__ D,
                                                       float* __restrict__ G) {
    const int idx = blockIdx.x * 256 + threadIdx.x;
    const int i = idx >> 10;
    const int j = (idx & 1023) << 2;
    if (i >= NN) return;

    const float* row0 = D + (size_t)i * NN + j;
    const bool hasR = (i + 1) < NN;
    const bool hasC = (j + 4) < NN;

    const float4 r0 = *reinterpret_cast<const float4*>(row0);
    float4 r1 = make_float4(0.f, 0.f, 0.f, 0.f);
    if (hasR) r1 = *reinterpret_cast<const float4*>(row0 + NN);
    const float s0 = hasC ? row0[4] : 0.f;
    const float s1 = (hasR && hasC) ? row0[NN + 4] : 0.f;

    const float a0 = dfun(r0.x), a1 = dfun(r0.y), a2 = dfun(r0.z), a3 = dfun(r0.w);
    const float a4 = hasC ? dfun(s0) : 0.f;
    const float b0 = hasR ? dfun(r1.x) : 0.f;
    const float b1 = hasR ? dfun(r1.y) : 0.f;
    const float b2 = hasR ? dfun(r1.z) : 0.f;
    const float b3 = hasR ? dfun(r1.w) : 0.f;
    const float b4 = (hasR && hasC) ? dfun(s1) : 0.f;

    float* go = G + (size_t)i * NN + j;
    go[0] = b1 + b0 + a1 - a0;
    go[1] = b2 + b1 + a2 - a1;
    go[2] = b3 + b2 + a3 - a2;
    go[3] = b4 + b3 + a4 - a3;
}

// ---------------------------------------------------------------------------
extern "C" void kernel_launch(void* const* d_in, const int* in_sizes, int n_in,
                              void* d_out, int out_size, void* d_ws, size_t ws_size,
                              hipStream_t stream) {
    (void)in_sizes; (void)n_in; (void)out_size;
    const float* D = (const float*)d_in[0];
    float* out = (float*)d_out;

    const size_t colbytes = (size_t)STRIPS * COLPITCH * sizeof(unsigned);
    const size_t sinkbytes = (size_t)STRIPS * SINKPITCH * sizeof(unsigned);
    const size_t ebytes = (size_t)NN * NN * sizeof(float);

    float* E = nullptr;
    unsigned *colbuf, *sink;
    if (ws_size >= ebytes + colbytes + sinkbytes) {
        E = (float*)d_ws;
        colbuf = (unsigned*)((char*)d_ws + ebytes);
        sink = (unsigned*)((char*)d_ws + ebytes + colbytes);
    } else if (ws_size >= colbytes + sinkbytes) {
        colbuf = (unsigned*)d_ws;
        sink = (unsigned*)((char*)d_ws + colbytes);
    } else {
        // fallback: live inside the grad region (rewritten by grad kernel,
        // stream-ordered after the DP)
        colbuf = (unsigned*)(out + 1);
        sink = colbuf + colbytes / 4;
    }

    hipMemsetAsync(colbuf, 0xFF, colbytes, stream);
    if (E) {
        exp_pre<<<2048, 256, 0, stream>>>(D, E);
        dtw_dp<0><<<STRIPS, 64, 0, stream>>>(E, out, colbuf, sink);
    } else {
        dtw_dp<1><<<STRIPS, 64, 0, stream>>>(D, out, colbuf, sink);
    }
    dtw_grad_kernel<<<dim3((NN * (NN / 4)) / 256), dim3(256), 0, stream>>>(D, out + 1);
}

// Round 7
// 523.647 us; speedup vs baseline: 3.7359x; 2.9441x over previous
//
#include <hip/hip_runtime.h>
#include <math.h>

#define NN 4096
#define STRIPS 32
#define SW 128                        // strip width (columns per workgroup)
#define RING_ROWS 128                 // power of 2: ring slot = row & 127
#define BATCH 32
#define NBATCH 130                    // (NN + 64) / BATCH
#define PAD 64                        // colbuf per-strip padding rows
#define COLPITCH (NN + 2 * PAD)
#define INFV 1e30f
#define SENTU 0xFFFFFFFFu             // memset(0xFF) sentinel, never a DP result

// lane l <- lane l-1 (whole-wave shift right by 1), VALU-latency cross-lane move
__device__ __forceinline__ float dpp_wave_shr1(float x) {
    return __int_as_float(__builtin_amdgcn_update_dpp(
        0, __float_as_int(x), 0x138 /*WAVE_SHR1*/, 0xf, 0xf, false));
}

// lanes 0..31 load boundary rows [row, row+32) of the left strip's column
__device__ __forceinline__ float bload(const unsigned* colL, int row, int lane) {
    float v = INFV;
    if (lane < 32 && row < NN) {
        unsigned u = __hip_atomic_load(colL + row, __ATOMIC_RELAXED,
                                       __HIP_MEMORY_SCOPE_AGENT);
        v = __uint_as_float(u);
    }
    return v;
}

// rows [rb, rb+32) still hold the memset sentinel? (rows >= NN masked off)
__device__ __forceinline__ bool has_sent(float b, int rb, int lane) {
    return __any((lane < 32) && ((rb + lane) < NN) &&
                 (__float_as_uint(b) == SENTU));
}

// async-stage rows [rb, rb+32) (128 cols) into the LDS ring at slot (row&127).
// 16 x global_load_lds (16B/lane); each covers 2 rows (lanes 0-31 / 32-63).
__device__ __forceinline__ void stageB(const float* Sg, float* ring, int rb,
                                       int lane) {
    #pragma unroll
    for (int k = 0; k < 16; ++k) {
        const int r0 = rb + 2 * k;
        if (r0 < NN) {
            const int slot = r0 & (RING_ROWS - 1);
            const float* gsrc =
                Sg + (size_t)(r0 + (lane >> 5)) * NN + ((lane & 31) << 2);
            __builtin_amdgcn_global_load_lds(
                (const __attribute__((address_space(1))) unsigned*)gsrc,
                (__attribute__((address_space(3))) unsigned*)((char*)ring +
                                                             slot * (SW * 4)),
                16, 0, 0);
        }
    }
}

#define CMP_BARRIER() do {                                          \
    asm volatile("s_waitcnt lgkmcnt(0)" ::: "memory");              \
    __builtin_amdgcn_s_barrier();                                   \
    asm volatile("" ::: "memory");                                  \
} while (0)

#define SUP_BARRIER() do {                                          \
    asm volatile("s_waitcnt vmcnt(0) lgkmcnt(0)" ::: "memory");     \
    __builtin_amdgcn_s_barrier();                                   \
    asm volatile("" ::: "memory");                                  \
} while (0)

// ---------------------------------------------------------------------------
// Producer/consumer DP: 32 workgroups x 2 waves. Strip g owns cols
// [128g, 128g+128); compute-wave lane l owns cols 2l, 2l+1; at step t lane l
// computes row r = t - l. Left/diag deps via DPP wave_shr1 (register chain).
//
// Compute wave (tid<64): NO vmem in the loop. Per batch: 32 grouped ds_reads
//   -> 32-step chain -> per-step outbox LDS write (lane63 real, others dummy)
//   -> barrier. Boundary values arrive via LDS inbox (read + 2x readlane/step).
// Support wave (tid>=64): per batch, all off the compute critical path:
//   - validate boundary rows [tb+32,tb+64) (loaded last batch), ds_write to
//     inbox[(n+1)&1]; prefetch rows [tb+64,tb+96) (2 batches ahead)
//   - agent-store previous batch's outbox (rows [32(n-1)-63, 32(n-1)-32]) to
//     this strip's column
//   - stage E rows [tb+32,tb+64) into the ring; vmcnt(0) drain inside its own
//     pre-barrier wait guarantees landing before compute reads them.
// Ring span check: compute batch n reads rows [tb-63, tb+31] (95 slots);
// support stages [tb+32, tb+64) (32 slots); disjoint within 128.
// Strip->block remap g=(b&7)*4+b/8 keeps 24/31 handoffs intra-XCD (shared L2).
// ---------------------------------------------------------------------------
template <int DOEXP>
__global__ __launch_bounds__(128, 1) void dtw_dp(const float* __restrict__ S,
                                                 float* __restrict__ cost_out,
                                                 unsigned* __restrict__ colbuf) {
    __shared__ float ring[RING_ROWS * SW];   // 64 KB
    __shared__ float inbox[2][32];
    __shared__ float outbox[2][32];
    __shared__ float outdummy[64];

    const int tid = threadIdx.x;
    const int lane = tid & 63;
    const int b = blockIdx.x;
    const int g = ((b & 7) << 2) | (b >> 3);   // XCD-affinity strip remap

    const float* Sg = S + g * SW;
    const unsigned* colL = colbuf + (size_t)(g - 1) * COLPITCH + PAD;
    unsigned* colM = colbuf + (size_t)g * COLPITCH + PAD;

    if (tid < 64) {
        // ================= compute wave =================
        // clear pre-start ring slots [64,128): rows r<0 read 0 (INF+0=INF)
        {
            const float4 z = make_float4(0.f, 0.f, 0.f, 0.f);
            float4* r4 = reinterpret_cast<float4*>(&ring[64 * SW]);
            #pragma unroll
            for (int i = 0; i < 32; ++i) r4[i * 64 + lane] = z;
        }
        CMP_BARRIER();   // prologue barrier

        const bool lane0 = (lane == 0);
        const int ostep = (lane == 63) ? 1 : 0;
        float cur0 = INFV, cur1 = INFV;   // my c[r-1][2l], c[r-1][2l+1]
        float l1s = INFV, l2s = INFV;     // lane l-1's c1 from t-1, t-2
        float bprevc = INFV;              // boundary carry (row tb-1)
        float save = 0.f;

        for (int n = 0; n < NBATCH; ++n) {
            const int tb = n << 5;
            const float binb = inbox[n & 1][lane & 31];

            float2 rv[BATCH];
            #pragma unroll
            for (int s = 0; s < BATCH; ++s) {
                const int r = tb + s - lane;
                rv[s] = *reinterpret_cast<const float2*>(
                    &ring[(r & (RING_ROWS - 1)) * SW + 2 * lane]);
            }
            __builtin_amdgcn_sched_barrier(0);

            float* obp = (lane == 63) ? &outbox[n & 1][0] : &outdummy[lane];
            float pbc = INFV;
            #pragma unroll
            for (int s = 0; s < BATCH; ++s) {
                float e0, e1;
                if (DOEXP) { e0 = __expf(-rv[s].x); e1 = __expf(-rv[s].y); }
                else       { e0 = rv[s].x;          e1 = rv[s].y; }

                float bcur;
                if (g == 0)
                    bcur = (n == 0 && s == 0) ? 0.f : INFV;  // (0,0) corner
                else
                    bcur = __int_as_float(
                        __builtin_amdgcn_readlane(__float_as_int(binb), s));
                const float bpv =
                    (g == 0) ? INFV : ((s == 0) ? bprevc : pbc);

                // chain: cndmask -> min3 -> add -> fmin -> add -> dpp
                const float L1 = lane0 ? bcur : l1s;   // c[r][col-1]
                const float L2 = lane0 ? bpv : l2s;    // c[r-1][col-1]
                const float m0 = fminf(fminf(L1, cur0), L2);
                const float c0 = e0 + m0;
                const float c1 = e1 + fminf(c0, fminf(cur0, cur1));
                *obp = c1;                 // lane63 -> outbox[s], rest -> dummy
                obp += ostep;
                const float sh = dpp_wave_shr1(c1);
                l2s = l1s; l1s = sh;
                cur0 = c0; cur1 = c1;
                pbc = bcur;
                if (s == 30) save = c1;    // final cell: n=129, s=30 (r=4095)
            }
            bprevc = pbc;
            CMP_BARRIER();
        }
        if (g == STRIPS - 1 && lane == 63) cost_out[0] = save;
    } else {
        // ================= support wave =================
        stageB(Sg, ring, 0, lane);                    // rows [0,32)
        float qv = INFV;
        if (g > 0) {
            qv = bload(colL, lane, lane);             // rows [0,32)
            while (has_sent(qv, 0, lane)) qv = bload(colL, lane, lane);
            if (lane < 32) inbox[0][lane] = qv;
            qv = bload(colL, 32 + lane, lane);        // prefetch rows [32,64)
        }
        SUP_BARRIER();   // prologue barrier

        for (int n = 0; n < NBATCH; ++n) {
            const int tb = n << 5;
            if (g > 0) {
                // validate rows [tb+32, tb+64) (for compute batch n+1)
                const int vb = tb + 32;
                while (has_sent(qv, vb, lane)) qv = bload(colL, vb + lane, lane);
                if (lane < 32) inbox[(n + 1) & 1][lane] = qv;
                qv = bload(colL, tb + 64 + lane, lane);   // 2 batches ahead
            }
            // publish previous batch's outbox: rows [32(n-1)-63, 32(n-1)-32]
            if (n > 0 && lane < 32) {
                const int row = ((n - 1) << 5) - 63 + lane;
                __hip_atomic_store(colM + row,
                                   __float_as_uint(outbox[(n - 1) & 1][lane]),
                                   __ATOMIC_RELAXED, __HIP_MEMORY_SCOPE_AGENT);
            }
            stageB(Sg, ring, tb + 32, lane);          // rows for batch n+1
            SUP_BARRIER();   // vmcnt(0) drain => staged rows landed
        }
        // epilogue: publish the last batch's outbox (rows [4065, 4096])
        if (lane < 32) {
            const int row = ((NBATCH - 1) << 5) - 63 + lane;
            __hip_atomic_store(colM + row,
                               __float_as_uint(outbox[(NBATCH - 1) & 1][lane]),
                               __ATOMIC_RELAXED, __HIP_MEMORY_SCOPE_AGENT);
        }
    }
}

// ---------------------------------------------------------------------------
// E = exp(-D), elementwise, full-occupancy (memory-bound)
// ---------------------------------------------------------------------------
__global__ __launch_bounds__(256) void exp_pre(const float* __restrict__ D,
                                               float* __restrict__ E) {
    const int n4 = NN * NN / 4;
    for (int i = blockIdx.x * 256 + threadIdx.x; i < n4; i += 2048 * 256) {
        float4 v = reinterpret_cast<const float4*>(D)[i];
        v.x = __expf(-v.x); v.y = __expf(-v.y);
        v.z = __expf(-v.z); v.w = __expf(-v.w);
        reinterpret_cast<float4*>(E)[i] = v;
    }
}

// ---------------------------------------------------------------------------
// acc_grad[i,j] = d[i+1,j+1] + d[i+1,j] + d[i,j+1] - d[i,j],  d = exp(-exp(-D))
// ---------------------------------------------------------------------------
__device__ __forceinline__ float dfun(float x) { return __expf(-__expf(-x)); }

__global__ __launch_bounds__(256) void dtw_grad_kernel(const float* __restrict__ D,
                                                       float* __restrict__ G) {
    const int idx = blockIdx.x * 256 + threadIdx.x;
    const int i = idx >> 10;
    const int j = (idx & 1023) << 2;
    if (i >= NN) return;

    const float* row0 = D + (size_t)i * NN + j;
    const bool hasR = (i + 1) < NN;
    const bool hasC = (j + 4) < NN;

    const float4 r0 = *reinterpret_cast<const float4*>(row0);
    float4 r1 = make_float4(0.f, 0.f, 0.f, 0.f);
    if (hasR) r1 = *reinterpret_cast<const float4*>(row0 + NN);
    const float s0 = hasC ? row0[4] : 0.f;
    const float s1 = (hasR && hasC) ? row0[NN + 4] : 0.f;

    const float a0 = dfun(r0.x), a1 = dfun(r0.y), a2 = dfun(r0.z), a3 = dfun(r0.w);
    const float a4 = hasC ? dfun(s0) : 0.f;
    const float b0 = hasR ? dfun(r1.x) : 0.f;
    const float b1 = hasR ? dfun(r1.y) : 0.f;
    const float b2 = hasR ? dfun(r1.z) : 0.f;
    const float b3 = hasR ? dfun(r1.w) : 0.f;
    const float b4 = (hasR && hasC) ? dfun(s1) : 0.f;

    float* go = G + (size_t)i * NN + j;
    go[0] = b1 + b0 + a1 - a0;
    go[1] = b2 + b1 + a2 - a1;
    go[2] = b3 + b2 + a3 - a2;
    go[3] = b4 + b3 + a4 - a3;
}

// ---------------------------------------------------------------------------
extern "C" void kernel_launch(void* const* d_in, const int* in_sizes, int n_in,
                              void* d_out, int out_size, void* d_ws, size_t ws_size,
                              hipStream_t stream) {
    (void)in_sizes; (void)n_in; (void)out_size;
    const float* D = (const float*)d_in[0];
    float* out = (float*)d_out;

    const size_t colbytes = (size_t)STRIPS * COLPITCH * sizeof(unsigned);
    const size_t ebytes = (size_t)NN * NN * sizeof(float);

    float* E = nullptr;
    unsigned* colbuf;
    if (ws_size >= ebytes + colbytes) {
        E = (float*)d_ws;
        colbuf = (unsigned*)((char*)d_ws + ebytes);
    } else if (ws_size >= colbytes) {
        colbuf = (unsigned*)d_ws;
    } else {
        // fallback: live inside the grad region (rewritten by grad kernel,
        // stream-ordered after the DP)
        colbuf = (unsigned*)(out + 1);
    }

    hipMemsetAsync(colbuf, 0xFF, colbytes, stream);
    if (E) {
        exp_pre<<<2048, 256, 0, stream>>>(D, E);
        dtw_dp<0><<<STRIPS, 128, 0, stream>>>(E, out, colbuf);
    } else {
        dtw_dp<1><<<STRIPS, 128, 0, stream>>>(D, out, colbuf);
    }
    dtw_grad_kernel<<<dim3((NN * (NN / 4)) / 256), dim3(256), 0, stream>>>(D, out + 1);
}

// Round 8
// 465.787 us; speedup vs baseline: 4.2000x; 1.1242x over previous
//
#include <hip/hip_runtime.h>
#include <math.h>

#define NN 4096
#define STRIPS 32
#define SW 128                        // strip width (columns per workgroup)
#define RING_ROWS 256                 // power of 2: slot = row & 255
#define RINGB (RING_ROWS * SW * 4)    // 131072 B
#define BATCH 32
#define NBATCH 130                    // (NN + 64) / BATCH
#define PAD 64                        // colbuf per-strip padding rows
#define COLPITCH (NN + 2 * PAD)
#define INFV 1e30f
#define SENTU 0xFFFFFFFFu             // memset(0xFF) sentinel, never a DP result

// lane l <- lane l-1 (whole-wave shift right by 1), VALU-latency cross-lane move
__device__ __forceinline__ float dpp_wave_shr1(float x) {
    return __int_as_float(__builtin_amdgcn_update_dpp(
        0, __float_as_int(x), 0x138 /*WAVE_SHR1*/, 0xf, 0xf, false));
}

// lanes 0..31 load boundary row (clamped): ALWAYS exactly 1 vmem instruction
// (exec = lanes 0-31, never empty), so counted vmcnt stays exact at the tail.
__device__ __forceinline__ float bload(const unsigned* colL, int row, int lane) {
    float v = INFV;
    const int rowc = (row < NN) ? row : (NN - 1);
    if (lane < 32) {
        unsigned u = __hip_atomic_load(colL + rowc, __ATOMIC_RELAXED,
                                       __HIP_MEMORY_SCOPE_AGENT);
        v = __uint_as_float(u);
    }
    return v;
}

// rows [rb, rb+32) still hold the memset sentinel? (rows >= NN masked off)
__device__ __forceinline__ bool has_sent(float b, int rb, int lane) {
    return __any((lane < 32) && ((rb + lane) < NN) &&
                 (__float_as_uint(b) == SENTU));
}

// async-stage rows [rb, rb+32) (128 cols) into the LDS ring at slot (row&255).
// ALWAYS exactly 16 global_load_lds (rows clamped to NN-2; slot from the
// UNCLAMPED row, which never collides with live rows: slots of [tb+64,tb+96)
// alias rows [tb-192,tb-160), outside the live window [tb-63, tb+96)).
__device__ __forceinline__ void stageB(const float* Sg, float* ring, int rb,
                                       int lane) {
    #pragma unroll
    for (int k = 0; k < 16; ++k) {
        const int r0 = rb + 2 * k;
        const int r0c = (r0 < NN - 1) ? r0 : (NN - 2);
        const int slot = r0 & (RING_ROWS - 1);
        const float* gsrc =
            Sg + (size_t)(r0c + (lane >> 5)) * NN + ((lane & 31) << 2);
        __builtin_amdgcn_global_load_lds(
            (const __attribute__((address_space(1))) unsigned*)gsrc,
            (__attribute__((address_space(3))) unsigned*)((char*)ring +
                                                         slot * (SW * 4)),
            16, 0, 0);
    }
}

// ---------------------------------------------------------------------------
// Producer/consumer DP: 32 workgroups x 2 waves. Strip g owns cols
// [128g, 128g+128); compute lane l owns cols 2l, 2l+1; at step t lane l
// computes row r = t - l. Left/diag deps via DPP wave_shr1 register chain.
//
// Compute wave: zero vmem. Per batch n: read inbox, ISSUE next batch's 32
//   ds_reads (rows staged 2 batches ahead -> always resident), 32-step chain
//   on the previous batch's registers, outbox LDS writes, barrier. Loop
//   unrolled x2 so rvA/rvB stay in registers (static indexing).
// Support wave: per batch n: validate boundary rows [tb+32,tb+64) (prefetched
//   last batch) -> inbox; prefetch [tb+64,tb+96); publish outbox[n-1]; stage
//   E rows [tb+64,tb+96); counted s_waitcnt vmcnt(18) (qv+publish+stage of
//   THIS batch) proves last batch's stage landed -- no vmcnt(0) drain, no
//   exposed HBM latency in the steady-state barrier period.
// ---------------------------------------------------------------------------
template <int DOEXP>
__global__ __launch_bounds__(128, 1) void dtw_dp(const float* __restrict__ S,
                                                 float* __restrict__ cost_out,
                                                 unsigned* __restrict__ colbuf) {
    __shared__ float ring[RING_ROWS * SW];   // 128 KB
    __shared__ float inbox[2][32];
    __shared__ float outbox[2][32];
    __shared__ float outdummy[64];

    const int tid = threadIdx.x;
    const int lane = tid & 63;
    const int b = blockIdx.x;
    const int g = ((b & 7) << 2) | (b >> 3);   // XCD-affinity strip remap

    const float* Sg = S + g * SW;
    const unsigned* colL = colbuf + (size_t)(g - 1) * COLPITCH + PAD;
    unsigned* colM = colbuf + (size_t)g * COLPITCH + PAD;

    if (tid < 64) {
        // ================= compute wave =================
        // clear pre-start ring slots [192,256): rows r<0 read 0 (INF+0=INF,
        // and avoids NaN bit patterns from uninitialized LDS)
        {
            const float4 z = make_float4(0.f, 0.f, 0.f, 0.f);
            float4* r4 = reinterpret_cast<float4*>(&ring[192 * SW]);
            #pragma unroll
            for (int i = 0; i < 32; ++i) r4[i * 64 + lane] = z;
        }
        asm volatile("s_waitcnt lgkmcnt(0)" ::: "memory");
        __builtin_amdgcn_s_barrier();   // prologue barrier

        const bool lane0 = (lane == 0);
        const int ostep = (lane == 63) ? 1 : 0;
        float cur0 = INFV, cur1 = INFV;   // my c[r-1][2l], c[r-1][2l+1]
        float l1s = INFV, l2s = INFV;     // lane l-1's c1 from t-1, t-2
        float bprevc = INFV;              // boundary carry (row tb-1)
        float save = 0.f;

        // per-lane ring byte address of (row tb-lane, col 2*lane), batch 0
        unsigned caddr = ((unsigned)((0 - lane) & (RING_ROWS - 1)) << 9) |
                         ((unsigned)lane << 3);

        // issue batch 0's reads (rows [-63, 31]: staged/cleared at prologue)
        float2 rvA[BATCH], rvB[BATCH];
        #pragma unroll
        for (int s = 0; s < BATCH; ++s)
            rvA[s] = *reinterpret_cast<const float2*>(
                (const char*)ring + ((caddr + s * 512) & (RINGB - 1)));

#define CSTEP(CUR, NXT, NIDX) do {                                            \
        const int n_ = (NIDX);                                                \
        const float binb = inbox[n_ & 1][lane & 31];                          \
        _Pragma("unroll")                                                     \
        for (int s = 0; s < BATCH; ++s)                                       \
            NXT[s] = *reinterpret_cast<const float2*>(                        \
                (const char*)ring +                                           \
                ((caddr + 16384u + (unsigned)(s * 512)) & (RINGB - 1)));      \
        __builtin_amdgcn_sched_barrier(0);                                    \
        float* obp = (lane == 63) ? &outbox[n_ & 1][0] : &outdummy[lane];     \
        float pbc = INFV;                                                     \
        _Pragma("unroll")                                                     \
        for (int s = 0; s < BATCH; ++s) {                                     \
            float e0, e1;                                                     \
            if (DOEXP) { e0 = __expf(-CUR[s].x); e1 = __expf(-CUR[s].y); }    \
            else       { e0 = CUR[s].x;          e1 = CUR[s].y; }             \
            float bcur;                                                       \
            if (g == 0)                                                       \
                bcur = (n_ == 0 && s == 0) ? 0.f : INFV;                      \
            else                                                              \
                bcur = __int_as_float(                                        \
                    __builtin_amdgcn_readlane(__float_as_int(binb), s));      \
            const float bpv =                                                 \
                (g == 0) ? INFV : ((s == 0) ? bprevc : pbc);                  \
            const float L1 = lane0 ? bcur : l1s;                              \
            const float L2 = lane0 ? bpv : l2s;                               \
            const float m0 = fminf(fminf(L1, cur0), L2);                      \
            const float c0 = e0 + m0;                                         \
            const float c1 = e1 + fminf(c0, fminf(cur0, cur1));               \
            *obp = c1;                                                        \
            obp += ostep;                                                     \
            const float sh = dpp_wave_shr1(c1);                               \
            l2s = l1s; l1s = sh;                                              \
            cur0 = c0; cur1 = c1;                                             \
            pbc = bcur;                                                       \
            if (s == 30) save = c1;                                           \
        }                                                                     \
        bprevc = pbc;                                                         \
        caddr = (caddr + 16384u) & (RINGB - 1);                               \
        asm volatile("s_waitcnt lgkmcnt(0)" ::: "memory");                    \
        __builtin_amdgcn_s_barrier();                                         \
    } while (0)

        for (int i = 0; i < NBATCH / 2; ++i) {
            CSTEP(rvA, rvB, 2 * i);
            CSTEP(rvB, rvA, 2 * i + 1);
        }
#undef CSTEP

        if (g == STRIPS - 1 && lane == 63) cost_out[0] = save;
    } else {
        // ================= support wave =================
        stageB(Sg, ring, 0, lane);    // rows [0,32)  (compute batch 0 window)
        stageB(Sg, ring, 32, lane);   // rows [32,64) (compute batch 0 prefetch)
        float qv = INFV;
        if (g > 0) {
            qv = bload(colL, lane & 31, lane);
            while (has_sent(qv, 0, lane)) qv = bload(colL, lane & 31, lane);
            if (lane < 32) inbox[0][lane] = qv;
            qv = bload(colL, 32 + (lane & 31), lane);   // rows [32,64)
        }
        asm volatile("s_waitcnt vmcnt(0) lgkmcnt(0)" ::: "memory");
        __builtin_amdgcn_s_barrier();   // prologue barrier

        for (int n = 0; n < NBATCH; ++n) {
            const int tb = n << 5;
            if (g > 0) {
                // validate rows [tb+32, tb+64) (compute batch n+1's inbox)
                const int vb = tb + 32;
                while (has_sent(qv, vb, lane))
                    qv = bload(colL, vb + (lane & 31), lane);
                if (lane < 32) inbox[(n + 1) & 1][lane] = qv;
                qv = bload(colL, tb + 64 + (lane & 31), lane);  // 2 ahead
            }
            // publish previous batch's outbox: rows [32(n-1)-63, 32(n-1)-32]
            if (n > 0 && lane < 32) {
                const int row = ((n - 1) << 5) - 63 + lane;
                __hip_atomic_store(colM + row,
                                   __float_as_uint(outbox[(n - 1) & 1][lane]),
                                   __ATOMIC_RELAXED, __HIP_MEMORY_SCOPE_AGENT);
            }
            stageB(Sg, ring, tb + 64, lane);   // rows for compute batch n+2
            __builtin_amdgcn_sched_barrier(0);
            // counted wait: newest 18 (17 for g=0) = THIS batch's qv+publish+
            // stage; forces last batch's stage ([tb+32,tb+64)) complete.
            if (g > 0) asm volatile("s_waitcnt vmcnt(18)" ::: "memory");
            else       asm volatile("s_waitcnt vmcnt(17)" ::: "memory");
            __builtin_amdgcn_sched_barrier(0);
            asm volatile("s_waitcnt lgkmcnt(0)" ::: "memory");
            __builtin_amdgcn_s_barrier();
        }
        // epilogue: publish the last batch's outbox (rows [4065, 4096])
        if (lane < 32) {
            const int row = ((NBATCH - 1) << 5) - 63 + lane;
            __hip_atomic_store(colM + row,
                               __float_as_uint(outbox[(NBATCH - 1) & 1][lane]),
                               __ATOMIC_RELAXED, __HIP_MEMORY_SCOPE_AGENT);
        }
    }
}

// ---------------------------------------------------------------------------
// Fused: E = exp(-D)  AND  acc_grad[i,j] = d[i+1,j+1]+d[i+1,j]+d[i,j+1]-d[i,j]
// with d = exp(-exp(-D)) (zero-padded bottom/right). The grad's inner
// exp(-D) terms ARE the E values -- emit them instead of a separate pass.
// ---------------------------------------------------------------------------
__global__ __launch_bounds__(256) void eg_kernel(const float* __restrict__ D,
                                                 float* __restrict__ E,
                                                 float* __restrict__ G) {
    const int idx = blockIdx.x * 256 + threadIdx.x;
    const int i = idx >> 10;
    const int j = (idx & 1023) << 2;
    if (i >= NN) return;

    const float* row0 = D + (size_t)i * NN + j;
    const bool hasR = (i + 1) < NN;
    const bool hasC = (j + 4) < NN;

    const float4 r0 = *reinterpret_cast<const float4*>(row0);
    float4 r1 = make_float4(0.f, 0.f, 0.f, 0.f);
    if (hasR) r1 = *reinterpret_cast<const float4*>(row0 + NN);
    const float s0 = hasC ? row0[4] : 0.f;
    const float s1 = (hasR && hasC) ? row0[NN + 4] : 0.f;

    // E row i
    const float ex0 = __expf(-r0.x), ex1 = __expf(-r0.y);
    const float ex2 = __expf(-r0.z), ex3 = __expf(-r0.w);
    *reinterpret_cast<float4*>(E + (size_t)i * NN + j) =
        make_float4(ex0, ex1, ex2, ex3);

    // d values
    const float a0 = __expf(-ex0), a1 = __expf(-ex1);
    const float a2 = __expf(-ex2), a3 = __expf(-ex3);
    const float a4 = hasC ? __expf(-__expf(-s0)) : 0.f;
    const float b0 = hasR ? __expf(-__expf(-r1.x)) : 0.f;
    const float b1 = hasR ? __expf(-__expf(-r1.y)) : 0.f;
    const float b2 = hasR ? __expf(-__expf(-r1.z)) : 0.f;
    const float b3 = hasR ? __expf(-__expf(-r1.w)) : 0.f;
    const float b4 = (hasR && hasC) ? __expf(-__expf(-s1)) : 0.f;

    float* go = G + (size_t)i * NN + j;
    go[0] = b1 + b0 + a1 - a0;
    go[1] = b2 + b1 + a2 - a1;
    go[2] = b3 + b2 + a3 - a2;
    go[3] = b4 + b3 + a4 - a3;
}

// fallback grad (no-E path only)
__device__ __forceinline__ float dfun(float x) { return __expf(-__expf(-x)); }

__global__ __launch_bounds__(256) void dtw_grad_kernel(const float* __restrict__ D,
                                                       float* __restrict__ G) {
    const int idx = blockIdx.x * 256 + threadIdx.x;
    const int i = idx >> 10;
    const int j = (idx & 1023) << 2;
    if (i >= NN) return;

    const float* row0 = D + (size_t)i * NN + j;
    const bool hasR = (i + 1) < NN;
    const bool hasC = (j + 4) < NN;

    const float4 r0 = *reinterpret_cast<const float4*>(row0);
    float4 r1 = make_float4(0.f, 0.f, 0.f, 0.f);
    if (hasR) r1 = *reinterpret_cast<const float4*>(row0 + NN);
    const float s0 = hasC ? row0[4] : 0.f;
    const float s1 = (hasR && hasC) ? row0[NN + 4] : 0.f;

    const float a0 = dfun(r0.x), a1 = dfun(r0.y), a2 = dfun(r0.z), a3 = dfun(r0.w);
    const float a4 = hasC ? dfun(s0) : 0.f;
    const float b0 = hasR ? dfun(r1.x) : 0.f;
    const float b1 = hasR ? dfun(r1.y) : 0.f;
    const float b2 = hasR ? dfun(r1.z) : 0.f;
    const float b3 = hasR ? dfun(r1.w) : 0.f;
    const float b4 = (hasR && hasC) ? dfun(s1) : 0.f;

    float* go = G + (size_t)i * NN + j;
    go[0] = b1 + b0 + a1 - a0;
    go[1] = b2 + b1 + a2 - a1;
    go[2] = b3 + b2 + a3 - a2;
    go[3] = b4 + b3 + a4 - a3;
}

// ---------------------------------------------------------------------------
extern "C" void kernel_launch(void* const* d_in, const int* in_sizes, int n_in,
                              void* d_out, int out_size, void* d_ws, size_t ws_size,
                              hipStream_t stream) {
    (void)in_sizes; (void)n_in; (void)out_size;
    const float* D = (const float*)d_in[0];
    float* out = (float*)d_out;

    const size_t colbytes = (size_t)STRIPS * COLPITCH * sizeof(unsigned);
    const size_t ebytes = (size_t)NN * NN * sizeof(float);
    const int gblocks = (NN * (NN / 4)) / 256;

    if (ws_size >= ebytes + colbytes) {
        float* E = (float*)d_ws;
        unsigned* colbuf = (unsigned*)((char*)d_ws + ebytes);
        hipMemsetAsync(colbuf, 0xFF, colbytes, stream);
        eg_kernel<<<gblocks, 256, 0, stream>>>(D, E, out + 1);
        dtw_dp<0><<<STRIPS, 128, 0, stream>>>(E, out, colbuf);
    } else {
        unsigned* colbuf = (ws_size >= colbytes) ? (unsigned*)d_ws
                                                 : (unsigned*)(out + 1);
        hipMemsetAsync(colbuf, 0xFF, colbytes, stream);
        dtw_dp<1><<<STRIPS, 128, 0, stream>>>(D, out, colbuf);
        dtw_grad_kernel<<<gblocks, 256, 0, stream>>>(D, out + 1);
    }
}